// Round 11
// baseline (193.370 us; speedup 1.0000x reference)
//
#include <hip/hip_runtime.h>
#include <stdint.h>

// ---------------- constants ----------------
#define NCLS 20
#define SURV_CAP 2048
#define NB0 1200   // L0: 100 tiles(1024px) x 3 anchors x 4 class-quarters
#define NB1 300    // L1: 25 x 3 x 4
#define NB2 84     // L2: 7 x 3 x 4
#define NBLK (NB0 + NB1 + NB2)
#define STG_CAP 512
#define STG_TRIG 256

__device__ __forceinline__ float sigm_fast(float x) { return 1.0f / (1.0f + __expf(-x)); }
__device__ __forceinline__ float sigm_prec(float x) { return 1.0f / (1.0f + expf(-x)); }

// ws layout:
//  cntM : u32[192*16]  (64B-padded per (L,shard))            @ 0      (12288 B)
//  cntF : u32[192*16]                                        @ 12288  (12288 B)
//  misc : u32[16]  [4..6]=survivor counts                    @ 24576  (64 B)
//  hist : u32[3*4096]                                        @ 24640  (49152 B)
//  surv : u64[3*SURV_CAP]                                    @ 73792  (49152 B)
//  bufs : u64 regions                                        @ 122944

// ---------------- K1: streaming score pass (s > 0.7) + inline histogram ----------------
// Block = 1024 px x 1 anchor x 5 classes; 1584 blocks (~6/CU for TLP).
// Per-wave LDS stage, ballot-prefix append, one returning atomic per flush to a
// 64-way-sharded padded counter; fire-and-forget hist atomics for candidates only.
__global__ __launch_bounds__(256, 8) void k_score(
    const float* __restrict__ obj0, const float* __restrict__ cls0,
    const float* __restrict__ obj1, const float* __restrict__ cls1,
    const float* __restrict__ obj2, const float* __restrict__ cls2,
    unsigned int* cntM, unsigned int* hist,
    unsigned long long* buf0, unsigned long long* buf1, unsigned long long* buf2,
    int rc0, int rc1, int rc2)
{
    int b = blockIdx.x;
    int L, tile, a, q, W;
    const float *obj, *cls; unsigned long long* bufL; int rc;
    if (b < NB0) {
        L = 0; tile = b % 100; a = (b / 100) % 3; q = b / 300; W = 320;
        obj = obj0; cls = cls0; bufL = buf0; rc = rc0;
    } else if (b < NB0 + NB1) {
        int bb = b - NB0;
        L = 1; tile = bb % 25; a = (bb / 25) % 3; q = bb / 75; W = 160;
        obj = obj1; cls = cls1; bufL = buf1; rc = rc1;
    } else {
        int bb = b - NB0 - NB1;
        L = 2; tile = bb % 7; a = (bb / 7) % 3; q = bb / 21; W = 80;
        obj = obj2; cls = cls2; bufL = buf2; rc = rc2;
    }
    const int P = W * W;
    const int shard = b & 63;
    const int cidx = (L * 64 + shard) * 16;
    unsigned long long* gbuf = bufL + (size_t)shard * (size_t)rc;
    unsigned int* histL = hist + L * 4096;

    __shared__ unsigned long long stage[4][STG_CAP];   // 16 KB

    const int t = threadIdx.x;
    const int wid = t >> 6, lane = t & 63;
    unsigned long long* wstage = stage[wid];
    const unsigned long long lt = (lane == 63) ? 0x7FFFFFFFFFFFFFFFull
                                               : ((1ull << lane) - 1ull);

    const int p0 = tile * 1024 + t * 4;   // 4 px/thread; P%4==0 all levels
    const bool act = p0 < P;
    const int c0 = q * 5;

    float soA = 0.f, soB = 0.f, soC = 0.f, soD = 0.f;
    if (act) {
        float4 ov = *(const float4*)(obj + (size_t)a * P + p0);
        soA = sigm_fast(ov.x); soB = sigm_fast(ov.y);
        soC = sigm_fast(ov.z); soD = sigm_fast(ov.w);
    }

    unsigned int wbase = 0;    // wave-uniform running count (register)
    #pragma unroll
    for (int cc = 0; cc < 5; cc++) {
        int c = c0 + cc;
        float s0 = -1.f, s1 = -1.f, s2 = -1.f, s3 = -1.f;
        if (act) {
            float4 cv = *(const float4*)(cls + (size_t)(a * NCLS + c) * P + p0);
            s0 = soA * sigm_fast(cv.x);
            s1 = soB * sigm_fast(cv.y);
            s2 = soC * sigm_fast(cv.z);
            s3 = soD * sigm_fast(cv.w);
        }
        bool t0 = s0 > 0.7f, t1 = s1 > 0.7f, t2 = s2 > 0.7f, t3 = s3 > 0.7f;
        unsigned long long m0 = __ballot(t0);
        unsigned long long m1 = __ballot(t1);
        unsigned long long m2 = __ballot(t2);
        unsigned long long m3 = __ballot(t3);
        if (m0 | m1 | m2 | m3) {
            unsigned int n0 = (unsigned int)__popcll(m0);
            unsigned int n1 = (unsigned int)__popcll(m1);
            unsigned int n2 = (unsigned int)__popcll(m2);
            if (t0) {
                unsigned int bits = __float_as_uint(s0);
                unsigned int bin = (bits - 0x3F000000u) >> 11; if (bin > 4095u) bin = 4095u;
                atomicAdd(&histL[bin], 1u);
                unsigned int ti = (unsigned int)(((p0 + 0) * 3 + a) * NCLS + c);
                wstage[wbase + (unsigned int)__popcll(m0 & lt)] =
                    ((unsigned long long)bits << 32) | (unsigned long long)(0xFFFFFFFFu - ti);
            }
            if (t1) {
                unsigned int bits = __float_as_uint(s1);
                unsigned int bin = (bits - 0x3F000000u) >> 11; if (bin > 4095u) bin = 4095u;
                atomicAdd(&histL[bin], 1u);
                unsigned int ti = (unsigned int)(((p0 + 1) * 3 + a) * NCLS + c);
                wstage[wbase + n0 + (unsigned int)__popcll(m1 & lt)] =
                    ((unsigned long long)bits << 32) | (unsigned long long)(0xFFFFFFFFu - ti);
            }
            if (t2) {
                unsigned int bits = __float_as_uint(s2);
                unsigned int bin = (bits - 0x3F000000u) >> 11; if (bin > 4095u) bin = 4095u;
                atomicAdd(&histL[bin], 1u);
                unsigned int ti = (unsigned int)(((p0 + 2) * 3 + a) * NCLS + c);
                wstage[wbase + n0 + n1 + (unsigned int)__popcll(m2 & lt)] =
                    ((unsigned long long)bits << 32) | (unsigned long long)(0xFFFFFFFFu - ti);
            }
            if (t3) {
                unsigned int bits = __float_as_uint(s3);
                unsigned int bin = (bits - 0x3F000000u) >> 11; if (bin > 4095u) bin = 4095u;
                atomicAdd(&histL[bin], 1u);
                unsigned int ti = (unsigned int)(((p0 + 3) * 3 + a) * NCLS + c);
                wstage[wbase + n0 + n1 + n2 + (unsigned int)__popcll(m3 & lt)] =
                    ((unsigned long long)bits << 32) | (unsigned long long)(0xFFFFFFFFu - ti);
            }
            wbase += n0 + n1 + n2 + (unsigned int)__popcll(m3);
        }
        if (wbase >= STG_TRIG) {   // wave-uniform register check; rare
            unsigned int gb = 0;
            if (lane == 0) gb = atomicAdd(&cntM[cidx], wbase);
            gb = __shfl(gb, 0);
            for (unsigned int i = lane; i < wbase; i += 64) {
                unsigned int gp = gb + i;
                if (gp < (unsigned int)rc) gbuf[gp] = wstage[i];
            }
            wbase = 0;
        }
    }
    if (wbase > 0) {   // single final flush
        unsigned int gb = 0;
        if (lane == 0) gb = atomicAdd(&cntM[cidx], wbase);
        gb = __shfl(gb, 0);
        for (unsigned int i = lane; i < wbase; i += 64) {
            unsigned int gp = gb + i;
            if (gp < (unsigned int)rc) gbuf[gp] = wstage[i];
        }
    }
}

// ---------------- K2: fallback check (early-exit) + rare rescan ----------------
// 64 blocks; normal case: compute 3 totals, exit. Pathological (<100 candidates at
// a level): rescan 1/64 of that level, histogram [0.5,0.7], append complement.
__global__ __launch_bounds__(256) void k_fb(
    const float* __restrict__ obj0, const float* __restrict__ cls0,
    const float* __restrict__ obj1, const float* __restrict__ cls1,
    const float* __restrict__ obj2, const float* __restrict__ cls2,
    const unsigned int* __restrict__ cntM, unsigned int* cntF, unsigned int* hist,
    unsigned long long* buf0, unsigned long long* buf1, unsigned long long* buf2,
    int rc0, int rc1, int rc2)
{
    const int b = blockIdx.x;
    const int t = threadIdx.x;
    __shared__ unsigned int totS;

    for (int L = 0; L < 3; L++) {
        const int rc = (L == 0) ? rc0 : (L == 1 ? rc1 : rc2);
        if (t < 64) {
            unsigned int v = cntM[(L * 64 + t) * 16];
            if (v > (unsigned int)rc) v = (unsigned int)rc;
            #pragma unroll
            for (int off = 32; off; off >>= 1) v += __shfl_down(v, off);
            if (t == 0) totS = v;
        }
        __syncthreads();
        if (totS < 100u) {
            unsigned long long* bufL = (L == 0) ? buf0 : (L == 1 ? buf1 : buf2);
            const float* objL = (L == 0) ? obj0 : (L == 1 ? obj1 : obj2);
            const float* clsL = (L == 0) ? cls0 : (L == 1 ? cls1 : cls2);
            const int WL = (L == 0) ? 320 : (L == 1 ? 160 : 80);
            const int PL = WL * WL;
            unsigned int nMine = cntM[(L * 64 + b) * 16];
            if (nMine > (unsigned int)rc) nMine = (unsigned int)rc;
            unsigned long long* myreg = bufL + (size_t)b * (size_t)rc;
            long long tot = (long long)PL * 3 * NCLS;
            for (long long idx = (long long)b * 256 + t; idx < tot; idx += 64 * 256) {
                int c = (int)(idx % NCLS);
                long long pa = idx / NCLS;
                int a = (int)(pa % 3);
                int p = (int)(pa / 3);
                float s = sigm_fast(objL[(size_t)a * PL + p]) *
                          sigm_fast(clsL[(size_t)(a * NCLS + c) * PL + p]);
                if (!(s > 0.7f)) {   // exact complement of main test
                    if (s >= 0.5f) {
                        unsigned int bin = (__float_as_uint(s) - 0x3F000000u) >> 11;
                        if (bin > 4095u) bin = 4095u;
                        atomicAdd(&hist[L * 4096 + bin], 1u);
                    }
                    unsigned int ti = (unsigned int)((p * 3 + a) * NCLS + c);
                    unsigned long long key =
                        ((unsigned long long)__float_as_uint(s) << 32) |
                        (unsigned long long)(0xFFFFFFFFu - ti);
                    unsigned int pos = nMine + atomicAdd(&cntF[(L * 64 + b) * 16], 1u);
                    if (pos < (unsigned int)rc) myreg[pos] = key;
                }
            }
        }
        __syncthreads();
    }
}

// ---------------- K3: compact (192 blocks; redundant threshold scan) ----------------
__global__ __launch_bounds__(256) void k_compact(
    const unsigned int* __restrict__ cntM, const unsigned int* __restrict__ cntF,
    unsigned int* misc, const unsigned int* __restrict__ hist,
    const unsigned long long* __restrict__ buf0,
    const unsigned long long* __restrict__ buf1,
    const unsigned long long* __restrict__ buf2,
    int rc0, int rc1, int rc2,
    unsigned long long* surv)
{
    __shared__ unsigned int tselS;
    const int t = threadIdx.x;
    const int lane = t & 63;
    const int r = blockIdx.x;
    const int L = r >> 6, s = r & 63;

    if (t < 64) {   // wave 0: threshold scan for this block's level
        if (t == 0) tselS = 0u;
        const unsigned int* h = hist + L * 4096;
        unsigned int sm = 0;
        for (int k = 0; k < 64; k++) sm += h[4095 - (lane * 64 + k)];
        unsigned int incl = sm;
        #pragma unroll
        for (int off = 1; off < 64; off <<= 1) {
            unsigned int u = __shfl_up(incl, off);
            if (lane >= off) incl += u;
        }
        unsigned int excl = incl - sm;
        if (excl < 100u && incl >= 100u) {
            unsigned int cum = excl;
            for (int k = 0; k < 64; k++) {
                cum += h[4095 - (lane * 64 + k)];
                if (cum >= 100u) {
                    tselS = 0x3F000000u + ((unsigned int)(4095 - (lane * 64 + k)) << 11);
                    break;
                }
            }
        }
    }
    __syncthreads();

    const unsigned long long* bufL = (L == 0) ? buf0 : (L == 1 ? buf1 : buf2);
    int rc = (L == 0) ? rc0 : (L == 1 ? rc1 : rc2);
    unsigned int n = cntM[r * 16] + cntF[r * 16];
    if (n > (unsigned int)rc) n = (unsigned int)rc;
    unsigned int ts = tselS;
    const unsigned long long* rb = bufL + (size_t)s * (size_t)rc;

    for (unsigned int i = t; i < n; i += 256) {
        unsigned long long k = rb[i];
        bool takeIt = (unsigned int)(k >> 32) >= ts;
        unsigned long long m = __ballot(takeIt);
        if (takeIt) {
            int lead = __ffsll((long long)m) - 1;
            int pref = __popcll(m & ((1ull << lane) - 1ull));
            unsigned int base = 0;
            if (lane == lead) base = atomicAdd(&misc[4 + L], (unsigned int)__popcll(m));
            base = __shfl(base, lead);
            unsigned int pos = base + (unsigned int)pref;
            if (pos < SURV_CAP) surv[L * SURV_CAP + pos] = k;
        }
    }
}

// ---------------- K4: rank-select + decode + sort + supmat(LDS) + greedy + out ----------------
__global__ __launch_bounds__(512) void k_tail2(
    const unsigned int* __restrict__ misc,
    const unsigned long long* __restrict__ surv,
    const float* __restrict__ reg0, const float* __restrict__ reg1, const float* __restrict__ reg2,
    float* __restrict__ out)
{
    const int t = threadIdx.x;
    __shared__ unsigned long long svl[SURV_CAP];       // 16 KB
    __shared__ unsigned long long topk[300];
    __shared__ float bx[300][4];
    __shared__ float sc[300];
    __shared__ int   lb[300];
    __shared__ unsigned long long key2[300];
    __shared__ float sbx[300][4];
    __shared__ float ssc[300];
    __shared__ int   slb[300];
    __shared__ float sar[300];
    __shared__ unsigned long long supS[300][5];        // 12 KB
    __shared__ unsigned char keepA[300];

    for (int i = t; i < 300; i += 512) topk[i] = 0ull;
    __syncthreads();

    // rank-select per level (keys unique)
    for (int L = 0; L < 3; L++) {
        int n = (int)misc[4 + L]; if (n > SURV_CAP) n = SURV_CAP;
        const unsigned long long* sv = surv + L * SURV_CAP;
        for (int i = t; i < n; i += 512) svl[i] = sv[i];
        __syncthreads();
        for (int i = t; i < n; i += 512) {
            unsigned long long ki = svl[i];
            int r = 0;
            for (int j = 0; j < n; j++) r += (svl[j] > ki);
            if (r < 100) topk[L * 100 + r] = ki;
        }
        __syncthreads();
    }

    const int   Wl[3] = {320, 160, 80};
    const float Sl[3] = {8.f, 16.f, 32.f};
    const float AW[3][3] = {{12.f, 19.f, 40.f}, {36.f, 76.f, 72.f}, {142.f, 192.f, 459.f}};
    const float AH[3][3] = {{16.f, 36.f, 28.f}, {75.f, 55.f, 146.f}, {110.f, 243.f, 401.f}};

    // decode
    for (int i = t; i < 300; i += 512) {
        unsigned long long k = topk[i];
        int L = i / 100;
        float s = __uint_as_float((unsigned int)(k >> 32));
        unsigned int ti = 0xFFFFFFFFu - (unsigned int)k;
        float x1 = 0.f, y1 = 0.f, x2 = 0.f, y2 = 0.f; int c = 0;
        if (k != 0ull) {
            c = (int)(ti % NCLS);
            unsigned int na = ti / NCLS;
            int a = (int)(na % 3);
            int p = (int)(na / 3);
            int W = Wl[L]; int P = W * W;
            int px = p % W, py = p / W;
            const float* reg = (L == 0) ? reg0 : (L == 1 ? reg1 : reg2);
            float tx = reg[(a * 4 + 0) * P + p];
            float ty = reg[(a * 4 + 1) * P + p];
            float tw = reg[(a * 4 + 2) * P + p];
            float th = reg[(a * 4 + 3) * P + p];
            float st = Sl[L];
            float cx = (sigm_prec(tx) * 3.0f - 1.5f + ((float)px + 0.5f)) * st;
            float cy = (sigm_prec(ty) * 3.0f - 1.5f + ((float)py + 0.5f)) * st;
            float w = expf(tw) * AW[L][a];
            float h = expf(th) * AH[L][a];
            x1 = cx - 0.5f * w; y1 = cy - 0.5f * h; x2 = cx + 0.5f * w; y2 = cy + 0.5f * h;
        } else {
            s = 0.f;
        }
        bx[i][0] = x1; bx[i][1] = y1; bx[i][2] = x2; bx[i][3] = y2;
        sc[i] = s; lb[i] = c;
        key2[i] = (k & 0xFFFFFFFF00000000ull) | (unsigned long long)(299 - i);  // stable
    }
    __syncthreads();

    // sort by rank
    for (int i = t; i < 300; i += 512) {
        unsigned long long ki = key2[i];
        int r = 0;
        for (int j = 0; j < 300; j++) r += (key2[j] > ki);
        sbx[r][0] = bx[i][0]; sbx[r][1] = bx[i][1]; sbx[r][2] = bx[i][2]; sbx[r][3] = bx[i][3];
        ssc[r] = sc[i]; slb[r] = lb[i];
    }
    __syncthreads();
    for (int i = t; i < 300; i += 512)
        sar[i] = (sbx[i][2] - sbx[i][0]) * (sbx[i][3] - sbx[i][1]);
    __syncthreads();

    // suppression matrix into LDS: task = w*300 + i
    for (int task = t; task < 1500; task += 512) {
        int w = task / 300, i = task - w * 300;
        float ax1 = sbx[i][0], ay1 = sbx[i][1], ax2 = sbx[i][2], ay2 = sbx[i][3], aa = sar[i];
        int al = slb[i];
        int jmax = (w == 4) ? 44 : 64;
        unsigned long long acc = 0ull;
        for (int jb = 0; jb < jmax; jb++) {
            int j = w * 64 + jb;
            float xx1 = fmaxf(ax1, sbx[j][0]);
            float yy1 = fmaxf(ay1, sbx[j][1]);
            float xx2 = fminf(ax2, sbx[j][2]);
            float yy2 = fminf(ay2, sbx[j][3]);
            float iw = fmaxf(1e-10f, xx2 - xx1);
            float ih = fmaxf(1e-10f, yy2 - yy1);
            float inter = iw * ih;
            float iou = inter / (aa + sar[j] - inter);
            if (iou > 0.5f && al == slb[j]) acc |= (1ull << jb);
        }
        supS[i][w] = acc;
    }
    __syncthreads();

    // greedy NMS: wave 0, lane l owns columns {l, 64+l, ...}; supmat symmetry lets
    // each lane preload only its OWN rows (15 u64 regs) from LDS.
    if (t < 64) {
        const int l = t;
        unsigned int validb = 0;
        validb |= (ssc[l]       > 0.01f) ? 1u : 0u;
        validb |= (ssc[64 + l]  > 0.01f) ? 2u : 0u;
        validb |= (ssc[128 + l] > 0.01f) ? 4u : 0u;
        validb |= (ssc[192 + l] > 0.01f) ? 8u : 0u;
        validb |= ((256 + l < 300) ? (ssc[256 + l] > 0.01f) : false) ? 16u : 0u;

        unsigned long long m00 = supS[l][0];
        unsigned long long m10 = supS[64 + l][0],  m11 = supS[64 + l][1];
        unsigned long long m20 = supS[128 + l][0], m21 = supS[128 + l][1], m22 = supS[128 + l][2];
        unsigned long long m30 = supS[192 + l][0], m31 = supS[192 + l][1], m32 = supS[192 + l][2], m33 = supS[192 + l][3];
        unsigned long long m40 = 0, m41 = 0, m42 = 0, m43 = 0, m44 = 0;
        if (256 + l < 300) {
            m40 = supS[256 + l][0]; m41 = supS[256 + l][1]; m42 = supS[256 + l][2];
            m43 = supS[256 + l][3]; m44 = supS[256 + l][4];
        }

        unsigned int supb = 0;

        #pragma clang loop unroll(disable)
        for (int b = 0; b < 64; b++) {           // word 0
            unsigned int x = __shfl(supb | ~validb, b);
            if (!((x >> 0) & 1u)) {
                unsigned int gt = (l > b) ? 1u : 0u;
                supb |= (((unsigned int)(m00 >> b) & gt)) << 0;
                supb |= (((unsigned int)(m10 >> b) & 1u)) << 1;
                supb |= (((unsigned int)(m20 >> b) & 1u)) << 2;
                supb |= (((unsigned int)(m30 >> b) & 1u)) << 3;
                supb |= (((unsigned int)(m40 >> b) & 1u)) << 4;
            }
        }
        #pragma clang loop unroll(disable)
        for (int b = 0; b < 64; b++) {           // word 1
            unsigned int x = __shfl(supb | ~validb, b);
            if (!((x >> 1) & 1u)) {
                unsigned int gt = (l > b) ? 1u : 0u;
                supb |= (((unsigned int)(m11 >> b) & gt)) << 1;
                supb |= (((unsigned int)(m21 >> b) & 1u)) << 2;
                supb |= (((unsigned int)(m31 >> b) & 1u)) << 3;
                supb |= (((unsigned int)(m41 >> b) & 1u)) << 4;
            }
        }
        #pragma clang loop unroll(disable)
        for (int b = 0; b < 64; b++) {           // word 2
            unsigned int x = __shfl(supb | ~validb, b);
            if (!((x >> 2) & 1u)) {
                unsigned int gt = (l > b) ? 1u : 0u;
                supb |= (((unsigned int)(m22 >> b) & gt)) << 2;
                supb |= (((unsigned int)(m32 >> b) & 1u)) << 3;
                supb |= (((unsigned int)(m42 >> b) & 1u)) << 4;
            }
        }
        #pragma clang loop unroll(disable)
        for (int b = 0; b < 64; b++) {           // word 3
            unsigned int x = __shfl(supb | ~validb, b);
            if (!((x >> 3) & 1u)) {
                unsigned int gt = (l > b) ? 1u : 0u;
                supb |= (((unsigned int)(m33 >> b) & gt)) << 3;
                supb |= (((unsigned int)(m43 >> b) & 1u)) << 4;
            }
        }
        #pragma clang loop unroll(disable)
        for (int b = 0; b < 44; b++) {           // word 4 (cols 256..299)
            unsigned int x = __shfl(supb | ~validb, b);
            if (!((x >> 4) & 1u)) {
                unsigned int gt = (l > b) ? 1u : 0u;
                supb |= (((unsigned int)(m44 >> b) & gt)) << 4;
            }
        }

        unsigned int kp = (~supb) & validb;
        keepA[l]       = (unsigned char)(kp & 1u);
        keepA[64 + l]  = (unsigned char)((kp >> 1) & 1u);
        keepA[128 + l] = (unsigned char)((kp >> 2) & 1u);
        keepA[192 + l] = (unsigned char)((kp >> 3) & 1u);
        if (256 + l < 300) keepA[256 + l] = (unsigned char)((kp >> 4) & 1u);
    }
    __syncthreads();

    for (int i = t; i < 300; i += 512) {
        float kpf = keepA[i] ? 1.f : 0.f;
        out[i * 4 + 0] = sbx[i][0];
        out[i * 4 + 1] = sbx[i][1];
        out[i * 4 + 2] = sbx[i][2];
        out[i * 4 + 3] = sbx[i][3];
        out[1200 + i] = ssc[i] * kpf;
        out[1500 + i] = (float)slb[i];
        out[1800 + i] = kpf;
    }
}

// ---------------- launch ----------------
extern "C" void kernel_launch(void* const* d_in, const int* in_sizes, int n_in,
                              void* d_out, int out_size, void* d_ws, size_t ws_size,
                              hipStream_t stream)
{
    const float* obj0 = (const float*)d_in[0];
    const float* cls0 = (const float*)d_in[1];
    const float* reg0 = (const float*)d_in[2];
    const float* obj1 = (const float*)d_in[3];
    const float* cls1 = (const float*)d_in[4];
    const float* reg1 = (const float*)d_in[5];
    const float* obj2 = (const float*)d_in[6];
    const float* cls2 = (const float*)d_in[7];
    const float* reg2 = (const float*)d_in[8];

    char* ws = (char*)d_ws;
    unsigned int* cntM = (unsigned int*)ws;                            // 12288 B
    unsigned int* cntF = (unsigned int*)(ws + 12288);                  // 12288 B
    unsigned int* misc = (unsigned int*)(ws + 24576);                  // 64 B
    unsigned int* hist = (unsigned int*)(ws + 24640);                  // 49152 B
    unsigned long long* surv = (unsigned long long*)(ws + 73792);      // 49152 B
    const size_t off = 122944;

    size_t avail = (ws_size > off) ? (ws_size - off) : 0;
    long long ents = (long long)(avail / 8);
    long long cap0 = ents * 16 / 21; if (cap0 > 6144000LL) cap0 = 6144000LL;
    long long cap1 = ents * 4 / 21;  if (cap1 > 1536000LL) cap1 = 1536000LL;
    long long cap2 = ents * 1 / 21;  if (cap2 > 384000LL)  cap2 = 384000LL;
    int rc0 = (int)(cap0 / 64); if (rc0 < 1) rc0 = 1;
    int rc1 = (int)(cap1 / 64); if (rc1 < 1) rc1 = 1;
    int rc2 = (int)(cap2 / 64); if (rc2 < 1) rc2 = 1;

    unsigned long long* buf0 = (unsigned long long*)(ws + off);
    unsigned long long* buf1 = buf0 + (size_t)rc0 * 64;
    unsigned long long* buf2 = buf1 + (size_t)rc1 * 64;

    hipMemsetAsync(ws, 0, 73792, stream);   // cntM + cntF + misc + hist
    k_score<<<NBLK, 256, 0, stream>>>(obj0, cls0, obj1, cls1, obj2, cls2,
                                      cntM, hist, buf0, buf1, buf2, rc0, rc1, rc2);
    k_fb<<<64, 256, 0, stream>>>(obj0, cls0, obj1, cls1, obj2, cls2,
                                 cntM, cntF, hist, buf0, buf1, buf2, rc0, rc1, rc2);
    k_compact<<<192, 256, 0, stream>>>(cntM, cntF, misc, hist, buf0, buf1, buf2,
                                       rc0, rc1, rc2, surv);
    k_tail2<<<1, 512, 0, stream>>>(misc, surv, reg0, reg1, reg2, (float*)d_out);
}

// Round 12
// 183.562 us; speedup vs baseline: 1.0534x; 1.0534x over previous
//
#include <hip/hip_runtime.h>
#include <stdint.h>

// ---------------- constants ----------------
#define NCLS 20
#define SURV_CAP 2048
#define NB0 1200   // L0: 100 tiles(1024px) x 3 anchors x 4 class-quarters
#define NB1 300    // L1: 25 x 3 x 4
#define NB2 84     // L2: 7 x 3 x 4
#define NBLK (NB0 + NB1 + NB2)
#define STG_CAP 512
#define STG_TRIG 256

__device__ __forceinline__ float sigm_fast(float x) { return 1.0f / (1.0f + __expf(-x)); }
__device__ __forceinline__ float sigm_prec(float x) { return 1.0f / (1.0f + expf(-x)); }

// ws layout:
//  cntM : u32[192*16]  (64B-padded per (L,shard))            @ 0      (12288 B)
//  cntF : u32[192*16]                                        @ 12288  (12288 B)
//  misc : u32[16]  [4..6]=survivor counts                    @ 24576  (64 B)
//  hist : u32[3*4096]                                        @ 24640  (49152 B)
//  surv : u64[3*SURV_CAP]                                    @ 73792  (49152 B)
//  sortf: f32[300*8]                                         @ 122944 (9600 B)
//  supG : u64[300*5]                                         @ 132544 (12000 B)
//  bufs : u64 regions                                        @ 147456

// ---------------- K1: streaming score pass (s > 0.7) + inline histogram ----------------
__global__ __launch_bounds__(256, 8) void k_score(
    const float* __restrict__ obj0, const float* __restrict__ cls0,
    const float* __restrict__ obj1, const float* __restrict__ cls1,
    const float* __restrict__ obj2, const float* __restrict__ cls2,
    unsigned int* cntM, unsigned int* hist,
    unsigned long long* buf0, unsigned long long* buf1, unsigned long long* buf2,
    int rc0, int rc1, int rc2)
{
    int b = blockIdx.x;
    int L, tile, a, q, W;
    const float *obj, *cls; unsigned long long* bufL; int rc;
    if (b < NB0) {
        L = 0; tile = b % 100; a = (b / 100) % 3; q = b / 300; W = 320;
        obj = obj0; cls = cls0; bufL = buf0; rc = rc0;
    } else if (b < NB0 + NB1) {
        int bb = b - NB0;
        L = 1; tile = bb % 25; a = (bb / 25) % 3; q = bb / 75; W = 160;
        obj = obj1; cls = cls1; bufL = buf1; rc = rc1;
    } else {
        int bb = b - NB0 - NB1;
        L = 2; tile = bb % 7; a = (bb / 7) % 3; q = bb / 21; W = 80;
        obj = obj2; cls = cls2; bufL = buf2; rc = rc2;
    }
    const int P = W * W;
    const int shard = b & 63;
    const int cidx = (L * 64 + shard) * 16;
    unsigned long long* gbuf = bufL + (size_t)shard * (size_t)rc;
    unsigned int* histL = hist + L * 4096;

    __shared__ unsigned long long stage[4][STG_CAP];   // 16 KB

    const int t = threadIdx.x;
    const int wid = t >> 6, lane = t & 63;
    unsigned long long* wstage = stage[wid];
    const unsigned long long lt = (lane == 63) ? 0x7FFFFFFFFFFFFFFFull
                                               : ((1ull << lane) - 1ull);

    const int p0 = tile * 1024 + t * 4;   // 4 px/thread; P%4==0 all levels
    const bool act = p0 < P;
    const int c0 = q * 5;

    float soA = 0.f, soB = 0.f, soC = 0.f, soD = 0.f;
    if (act) {
        float4 ov = *(const float4*)(obj + (size_t)a * P + p0);
        soA = sigm_fast(ov.x); soB = sigm_fast(ov.y);
        soC = sigm_fast(ov.z); soD = sigm_fast(ov.w);
    }

    unsigned int wbase = 0;    // wave-uniform running count (register)
    #pragma unroll
    for (int cc = 0; cc < 5; cc++) {
        int c = c0 + cc;
        float s0 = -1.f, s1 = -1.f, s2 = -1.f, s3 = -1.f;
        if (act) {
            float4 cv = *(const float4*)(cls + (size_t)(a * NCLS + c) * P + p0);
            s0 = soA * sigm_fast(cv.x);
            s1 = soB * sigm_fast(cv.y);
            s2 = soC * sigm_fast(cv.z);
            s3 = soD * sigm_fast(cv.w);
        }
        bool t0 = s0 > 0.7f, t1 = s1 > 0.7f, t2 = s2 > 0.7f, t3 = s3 > 0.7f;
        unsigned long long m0 = __ballot(t0);
        unsigned long long m1 = __ballot(t1);
        unsigned long long m2 = __ballot(t2);
        unsigned long long m3 = __ballot(t3);
        if (m0 | m1 | m2 | m3) {
            unsigned int n0 = (unsigned int)__popcll(m0);
            unsigned int n1 = (unsigned int)__popcll(m1);
            unsigned int n2 = (unsigned int)__popcll(m2);
            if (t0) {
                unsigned int bits = __float_as_uint(s0);
                unsigned int bin = (bits - 0x3F000000u) >> 11; if (bin > 4095u) bin = 4095u;
                atomicAdd(&histL[bin], 1u);
                unsigned int ti = (unsigned int)(((p0 + 0) * 3 + a) * NCLS + c);
                wstage[wbase + (unsigned int)__popcll(m0 & lt)] =
                    ((unsigned long long)bits << 32) | (unsigned long long)(0xFFFFFFFFu - ti);
            }
            if (t1) {
                unsigned int bits = __float_as_uint(s1);
                unsigned int bin = (bits - 0x3F000000u) >> 11; if (bin > 4095u) bin = 4095u;
                atomicAdd(&histL[bin], 1u);
                unsigned int ti = (unsigned int)(((p0 + 1) * 3 + a) * NCLS + c);
                wstage[wbase + n0 + (unsigned int)__popcll(m1 & lt)] =
                    ((unsigned long long)bits << 32) | (unsigned long long)(0xFFFFFFFFu - ti);
            }
            if (t2) {
                unsigned int bits = __float_as_uint(s2);
                unsigned int bin = (bits - 0x3F000000u) >> 11; if (bin > 4095u) bin = 4095u;
                atomicAdd(&histL[bin], 1u);
                unsigned int ti = (unsigned int)(((p0 + 2) * 3 + a) * NCLS + c);
                wstage[wbase + n0 + n1 + (unsigned int)__popcll(m2 & lt)] =
                    ((unsigned long long)bits << 32) | (unsigned long long)(0xFFFFFFFFu - ti);
            }
            if (t3) {
                unsigned int bits = __float_as_uint(s3);
                unsigned int bin = (bits - 0x3F000000u) >> 11; if (bin > 4095u) bin = 4095u;
                atomicAdd(&histL[bin], 1u);
                unsigned int ti = (unsigned int)(((p0 + 3) * 3 + a) * NCLS + c);
                wstage[wbase + n0 + n1 + n2 + (unsigned int)__popcll(m3 & lt)] =
                    ((unsigned long long)bits << 32) | (unsigned long long)(0xFFFFFFFFu - ti);
            }
            wbase += n0 + n1 + n2 + (unsigned int)__popcll(m3);
        }
        if (wbase >= STG_TRIG) {   // wave-uniform register check; rare
            unsigned int gb = 0;
            if (lane == 0) gb = atomicAdd(&cntM[cidx], wbase);
            gb = __shfl(gb, 0);
            for (unsigned int i = lane; i < wbase; i += 64) {
                unsigned int gp = gb + i;
                if (gp < (unsigned int)rc) gbuf[gp] = wstage[i];
            }
            wbase = 0;
        }
    }
    if (wbase > 0) {   // single final flush
        unsigned int gb = 0;
        if (lane == 0) gb = atomicAdd(&cntM[cidx], wbase);
        gb = __shfl(gb, 0);
        for (unsigned int i = lane; i < wbase; i += 64) {
            unsigned int gp = gb + i;
            if (gp < (unsigned int)rc) gbuf[gp] = wstage[i];
        }
    }
}

// ---------------- K2: fallback check (early-exit) + rare rescan ----------------
__global__ __launch_bounds__(256) void k_fb(
    const float* __restrict__ obj0, const float* __restrict__ cls0,
    const float* __restrict__ obj1, const float* __restrict__ cls1,
    const float* __restrict__ obj2, const float* __restrict__ cls2,
    const unsigned int* __restrict__ cntM, unsigned int* cntF, unsigned int* hist,
    unsigned long long* buf0, unsigned long long* buf1, unsigned long long* buf2,
    int rc0, int rc1, int rc2)
{
    const int b = blockIdx.x;
    const int t = threadIdx.x;
    __shared__ unsigned int totS;

    for (int L = 0; L < 3; L++) {
        const int rc = (L == 0) ? rc0 : (L == 1 ? rc1 : rc2);
        if (t < 64) {
            unsigned int v = cntM[(L * 64 + t) * 16];
            if (v > (unsigned int)rc) v = (unsigned int)rc;
            #pragma unroll
            for (int off = 32; off; off >>= 1) v += __shfl_down(v, off);
            if (t == 0) totS = v;
        }
        __syncthreads();
        if (totS < 100u) {
            unsigned long long* bufL = (L == 0) ? buf0 : (L == 1 ? buf1 : buf2);
            const float* objL = (L == 0) ? obj0 : (L == 1 ? obj1 : obj2);
            const float* clsL = (L == 0) ? cls0 : (L == 1 ? cls1 : cls2);
            const int WL = (L == 0) ? 320 : (L == 1 ? 160 : 80);
            const int PL = WL * WL;
            unsigned int nMine = cntM[(L * 64 + b) * 16];
            if (nMine > (unsigned int)rc) nMine = (unsigned int)rc;
            unsigned long long* myreg = bufL + (size_t)b * (size_t)rc;
            long long tot = (long long)PL * 3 * NCLS;
            for (long long idx = (long long)b * 256 + t; idx < tot; idx += 64 * 256) {
                int c = (int)(idx % NCLS);
                long long pa = idx / NCLS;
                int a = (int)(pa % 3);
                int p = (int)(pa / 3);
                float s = sigm_fast(objL[(size_t)a * PL + p]) *
                          sigm_fast(clsL[(size_t)(a * NCLS + c) * PL + p]);
                if (!(s > 0.7f)) {   // exact complement of main test
                    if (s >= 0.5f) {
                        unsigned int bin = (__float_as_uint(s) - 0x3F000000u) >> 11;
                        if (bin > 4095u) bin = 4095u;
                        atomicAdd(&hist[L * 4096 + bin], 1u);
                    }
                    unsigned int ti = (unsigned int)((p * 3 + a) * NCLS + c);
                    unsigned long long key =
                        ((unsigned long long)__float_as_uint(s) << 32) |
                        (unsigned long long)(0xFFFFFFFFu - ti);
                    unsigned int pos = nMine + atomicAdd(&cntF[(L * 64 + b) * 16], 1u);
                    if (pos < (unsigned int)rc) myreg[pos] = key;
                }
            }
        }
        __syncthreads();
    }
}

// ---------------- K3: compact (192 blocks; redundant threshold scan) ----------------
__global__ __launch_bounds__(256) void k_compact(
    const unsigned int* __restrict__ cntM, const unsigned int* __restrict__ cntF,
    unsigned int* misc, const unsigned int* __restrict__ hist,
    const unsigned long long* __restrict__ buf0,
    const unsigned long long* __restrict__ buf1,
    const unsigned long long* __restrict__ buf2,
    int rc0, int rc1, int rc2,
    unsigned long long* surv)
{
    __shared__ unsigned int tselS;
    const int t = threadIdx.x;
    const int lane = t & 63;
    const int r = blockIdx.x;
    const int L = r >> 6, s = r & 63;

    if (t < 64) {   // wave 0: threshold scan for this block's level
        if (t == 0) tselS = 0u;
        const unsigned int* h = hist + L * 4096;
        unsigned int sm = 0;
        for (int k = 0; k < 64; k++) sm += h[4095 - (lane * 64 + k)];
        unsigned int incl = sm;
        #pragma unroll
        for (int off = 1; off < 64; off <<= 1) {
            unsigned int u = __shfl_up(incl, off);
            if (lane >= off) incl += u;
        }
        unsigned int excl = incl - sm;
        if (excl < 100u && incl >= 100u) {
            unsigned int cum = excl;
            for (int k = 0; k < 64; k++) {
                cum += h[4095 - (lane * 64 + k)];
                if (cum >= 100u) {
                    tselS = 0x3F000000u + ((unsigned int)(4095 - (lane * 64 + k)) << 11);
                    break;
                }
            }
        }
    }
    __syncthreads();

    const unsigned long long* bufL = (L == 0) ? buf0 : (L == 1 ? buf1 : buf2);
    int rc = (L == 0) ? rc0 : (L == 1 ? rc1 : rc2);
    unsigned int n = cntM[r * 16] + cntF[r * 16];
    if (n > (unsigned int)rc) n = (unsigned int)rc;
    unsigned int ts = tselS;
    const unsigned long long* rb = bufL + (size_t)s * (size_t)rc;

    for (unsigned int i = t; i < n; i += 256) {
        unsigned long long k = rb[i];
        bool takeIt = (unsigned int)(k >> 32) >= ts;
        unsigned long long m = __ballot(takeIt);
        if (takeIt) {
            int lead = __ffsll((long long)m) - 1;
            int pref = __popcll(m & ((1ull << lane) - 1ull));
            unsigned int base = 0;
            if (lane == lead) base = atomicAdd(&misc[4 + L], (unsigned int)__popcll(m));
            base = __shfl(base, lead);
            unsigned int pos = base + (unsigned int)pref;
            if (pos < SURV_CAP) surv[L * SURV_CAP + pos] = k;
        }
    }
}

// ---------------- K4: rank-select + decode + sort -> sortf[300][8] ----------------
__global__ __launch_bounds__(512) void k_rank(
    const unsigned int* __restrict__ misc,
    const unsigned long long* __restrict__ surv,
    const float* __restrict__ reg0, const float* __restrict__ reg1, const float* __restrict__ reg2,
    float* __restrict__ sortf)
{
    const int t = threadIdx.x;
    __shared__ unsigned long long svl[SURV_CAP];
    __shared__ unsigned long long topk[300];
    __shared__ float bx[300][4];
    __shared__ float sc[300];
    __shared__ int   lb[300];
    __shared__ unsigned long long key2[300];

    for (int i = t; i < 300; i += 512) topk[i] = 0ull;
    __syncthreads();

    for (int L = 0; L < 3; L++) {
        int n = (int)misc[4 + L]; if (n > SURV_CAP) n = SURV_CAP;
        const unsigned long long* sv = surv + L * SURV_CAP;
        for (int i = t; i < n; i += 512) svl[i] = sv[i];
        __syncthreads();
        for (int i = t; i < n; i += 512) {
            unsigned long long ki = svl[i];
            int r = 0;
            for (int j = 0; j < n; j++) r += (svl[j] > ki);
            if (r < 100) topk[L * 100 + r] = ki;
        }
        __syncthreads();
    }

    const int   Wl[3] = {320, 160, 80};
    const float Sl[3] = {8.f, 16.f, 32.f};
    const float AW[3][3] = {{12.f, 19.f, 40.f}, {36.f, 76.f, 72.f}, {142.f, 192.f, 459.f}};
    const float AH[3][3] = {{16.f, 36.f, 28.f}, {75.f, 55.f, 146.f}, {110.f, 243.f, 401.f}};

    for (int i = t; i < 300; i += 512) {
        unsigned long long k = topk[i];
        int L = i / 100;
        float s = __uint_as_float((unsigned int)(k >> 32));
        unsigned int ti = 0xFFFFFFFFu - (unsigned int)k;
        float x1 = 0.f, y1 = 0.f, x2 = 0.f, y2 = 0.f; int c = 0;
        if (k != 0ull) {
            c = (int)(ti % NCLS);
            unsigned int na = ti / NCLS;
            int a = (int)(na % 3);
            int p = (int)(na / 3);
            int W = Wl[L]; int P = W * W;
            int px = p % W, py = p / W;
            const float* reg = (L == 0) ? reg0 : (L == 1 ? reg1 : reg2);
            float tx = reg[(a * 4 + 0) * P + p];
            float ty = reg[(a * 4 + 1) * P + p];
            float tw = reg[(a * 4 + 2) * P + p];
            float th = reg[(a * 4 + 3) * P + p];
            float st = Sl[L];
            float cx = (sigm_prec(tx) * 3.0f - 1.5f + ((float)px + 0.5f)) * st;
            float cy = (sigm_prec(ty) * 3.0f - 1.5f + ((float)py + 0.5f)) * st;
            float w = expf(tw) * AW[L][a];
            float h = expf(th) * AH[L][a];
            x1 = cx - 0.5f * w; y1 = cy - 0.5f * h; x2 = cx + 0.5f * w; y2 = cy + 0.5f * h;
        } else {
            s = 0.f;
        }
        bx[i][0] = x1; bx[i][1] = y1; bx[i][2] = x2; bx[i][3] = y2;
        sc[i] = s; lb[i] = c;
        key2[i] = (k & 0xFFFFFFFF00000000ull) | (unsigned long long)(299 - i);  // stable
    }
    __syncthreads();

    for (int i = t; i < 300; i += 512) {
        unsigned long long ki = key2[i];
        int r = 0;
        for (int j = 0; j < 300; j++) r += (key2[j] > ki);
        float* p = sortf + r * 8;
        p[0] = bx[i][0]; p[1] = bx[i][1]; p[2] = bx[i][2]; p[3] = bx[i][3];
        p[4] = sc[i]; p[5] = (float)lb[i]; p[6] = 0.f; p[7] = 0.f;
    }
}

// ---------------- K5: suppression matrix, 6 blocks x 256 ----------------
__global__ __launch_bounds__(256) void k_supmat(
    const float* __restrict__ sortf, unsigned long long* __restrict__ supG)
{
    __shared__ float sx1[300], sy1[300], sx2[300], sy2[300], sar[300];
    __shared__ int slb[300];
    const int t = threadIdx.x;
    for (int i = t; i < 300; i += 256) {
        float4 b = *(const float4*)(sortf + i * 8);
        sx1[i] = b.x; sy1[i] = b.y; sx2[i] = b.z; sy2[i] = b.w;
        sar[i] = (b.z - b.x) * (b.w - b.y);
        slb[i] = (int)sortf[i * 8 + 5];
    }
    __syncthreads();

    int task = blockIdx.x * 256 + t;
    if (task >= 1500) return;
    int w = task / 300, i = task - w * 300;
    float ax1 = sx1[i], ay1 = sy1[i], ax2 = sx2[i], ay2 = sy2[i], aa = sar[i];
    int al = slb[i];
    int jmax = (w == 4) ? 44 : 64;
    unsigned long long acc = 0ull;
    for (int jb = 0; jb < jmax; jb++) {
        int j = w * 64 + jb;
        float xx1 = fmaxf(ax1, sx1[j]);
        float yy1 = fmaxf(ay1, sy1[j]);
        float xx2 = fminf(ax2, sx2[j]);
        float yy2 = fminf(ay2, sy2[j]);
        float iw = fmaxf(1e-10f, xx2 - xx1);
        float ih = fmaxf(1e-10f, yy2 - yy1);
        float inter = iw * ih;
        float iou = inter / (aa + sar[j] - inter);
        if (iou > 0.5f && al == slb[j]) acc |= (1ull << jb);
    }
    supG[i * 5 + w] = acc;
}

// ---------------- K6: lane-parallel greedy NMS + output ----------------
__global__ __launch_bounds__(256) void k_greedy(
    const float* __restrict__ sortf, const unsigned long long* __restrict__ supG,
    float* __restrict__ out)
{
    const int t = threadIdx.x;
    __shared__ unsigned char keepA[300];

    if (t < 64) {
        const int l = t;
        unsigned int validb = 0;
        float s0 = sortf[(l) * 8 + 4];
        float s1 = sortf[(64 + l) * 8 + 4];
        float s2 = sortf[(128 + l) * 8 + 4];
        float s3 = sortf[(192 + l) * 8 + 4];
        float s4 = (256 + l < 300) ? sortf[(256 + l) * 8 + 4] : 0.f;
        validb |= (s0 > 0.01f) ? 1u : 0u;
        validb |= (s1 > 0.01f) ? 2u : 0u;
        validb |= (s2 > 0.01f) ? 4u : 0u;
        validb |= (s3 > 0.01f) ? 8u : 0u;
        validb |= (s4 > 0.01f) ? 16u : 0u;

        const unsigned long long* g = supG;
        unsigned long long m00 = g[(l) * 5 + 0];
        unsigned long long m10 = g[(64 + l) * 5 + 0],  m11 = g[(64 + l) * 5 + 1];
        unsigned long long m20 = g[(128 + l) * 5 + 0], m21 = g[(128 + l) * 5 + 1], m22 = g[(128 + l) * 5 + 2];
        unsigned long long m30 = g[(192 + l) * 5 + 0], m31 = g[(192 + l) * 5 + 1], m32 = g[(192 + l) * 5 + 2], m33 = g[(192 + l) * 5 + 3];
        unsigned long long m40 = 0, m41 = 0, m42 = 0, m43 = 0, m44 = 0;
        if (256 + l < 300) {
            m40 = g[(256 + l) * 5 + 0]; m41 = g[(256 + l) * 5 + 1]; m42 = g[(256 + l) * 5 + 2];
            m43 = g[(256 + l) * 5 + 3]; m44 = g[(256 + l) * 5 + 4];
        }

        unsigned int supb = 0;

        #pragma clang loop unroll(disable)
        for (int b = 0; b < 64; b++) {           // word 0
            unsigned int x = __shfl(supb | ~validb, b);
            if (!((x >> 0) & 1u)) {
                unsigned int gt = (l > b) ? 1u : 0u;
                supb |= (((unsigned int)(m00 >> b) & gt)) << 0;
                supb |= (((unsigned int)(m10 >> b) & 1u)) << 1;
                supb |= (((unsigned int)(m20 >> b) & 1u)) << 2;
                supb |= (((unsigned int)(m30 >> b) & 1u)) << 3;
                supb |= (((unsigned int)(m40 >> b) & 1u)) << 4;
            }
        }
        #pragma clang loop unroll(disable)
        for (int b = 0; b < 64; b++) {           // word 1
            unsigned int x = __shfl(supb | ~validb, b);
            if (!((x >> 1) & 1u)) {
                unsigned int gt = (l > b) ? 1u : 0u;
                supb |= (((unsigned int)(m11 >> b) & gt)) << 1;
                supb |= (((unsigned int)(m21 >> b) & 1u)) << 2;
                supb |= (((unsigned int)(m31 >> b) & 1u)) << 3;
                supb |= (((unsigned int)(m41 >> b) & 1u)) << 4;
            }
        }
        #pragma clang loop unroll(disable)
        for (int b = 0; b < 64; b++) {           // word 2
            unsigned int x = __shfl(supb | ~validb, b);
            if (!((x >> 2) & 1u)) {
                unsigned int gt = (l > b) ? 1u : 0u;
                supb |= (((unsigned int)(m22 >> b) & gt)) << 2;
                supb |= (((unsigned int)(m32 >> b) & 1u)) << 3;
                supb |= (((unsigned int)(m42 >> b) & 1u)) << 4;
            }
        }
        #pragma clang loop unroll(disable)
        for (int b = 0; b < 64; b++) {           // word 3
            unsigned int x = __shfl(supb | ~validb, b);
            if (!((x >> 3) & 1u)) {
                unsigned int gt = (l > b) ? 1u : 0u;
                supb |= (((unsigned int)(m33 >> b) & gt)) << 3;
                supb |= (((unsigned int)(m43 >> b) & 1u)) << 4;
            }
        }
        #pragma clang loop unroll(disable)
        for (int b = 0; b < 44; b++) {           // word 4 (cols 256..299)
            unsigned int x = __shfl(supb | ~validb, b);
            if (!((x >> 4) & 1u)) {
                unsigned int gt = (l > b) ? 1u : 0u;
                supb |= (((unsigned int)(m44 >> b) & gt)) << 4;
            }
        }

        unsigned int kp = (~supb) & validb;
        keepA[l]       = (unsigned char)(kp & 1u);
        keepA[64 + l]  = (unsigned char)((kp >> 1) & 1u);
        keepA[128 + l] = (unsigned char)((kp >> 2) & 1u);
        keepA[192 + l] = (unsigned char)((kp >> 3) & 1u);
        if (256 + l < 300) keepA[256 + l] = (unsigned char)((kp >> 4) & 1u);
    }
    __syncthreads();

    for (int i = t; i < 300; i += 256) {
        const float* p = sortf + i * 8;
        float kpf = keepA[i] ? 1.f : 0.f;
        out[i * 4 + 0] = p[0];
        out[i * 4 + 1] = p[1];
        out[i * 4 + 2] = p[2];
        out[i * 4 + 3] = p[3];
        out[1200 + i] = p[4] * kpf;
        out[1500 + i] = p[5];
        out[1800 + i] = kpf;
    }
}

// ---------------- launch ----------------
extern "C" void kernel_launch(void* const* d_in, const int* in_sizes, int n_in,
                              void* d_out, int out_size, void* d_ws, size_t ws_size,
                              hipStream_t stream)
{
    const float* obj0 = (const float*)d_in[0];
    const float* cls0 = (const float*)d_in[1];
    const float* reg0 = (const float*)d_in[2];
    const float* obj1 = (const float*)d_in[3];
    const float* cls1 = (const float*)d_in[4];
    const float* reg1 = (const float*)d_in[5];
    const float* obj2 = (const float*)d_in[6];
    const float* cls2 = (const float*)d_in[7];
    const float* reg2 = (const float*)d_in[8];

    char* ws = (char*)d_ws;
    unsigned int* cntM = (unsigned int*)ws;                            // 12288 B
    unsigned int* cntF = (unsigned int*)(ws + 12288);                  // 12288 B
    unsigned int* misc = (unsigned int*)(ws + 24576);                  // 64 B
    unsigned int* hist = (unsigned int*)(ws + 24640);                  // 49152 B
    unsigned long long* surv = (unsigned long long*)(ws + 73792);      // 49152 B
    float* sortf = (float*)(ws + 122944);                              // 9600 B
    unsigned long long* supG = (unsigned long long*)(ws + 132544);     // 12000 B
    const size_t off = 147456;

    size_t avail = (ws_size > off) ? (ws_size - off) : 0;
    long long ents = (long long)(avail / 8);
    long long cap0 = ents * 16 / 21; if (cap0 > 6144000LL) cap0 = 6144000LL;
    long long cap1 = ents * 4 / 21;  if (cap1 > 1536000LL) cap1 = 1536000LL;
    long long cap2 = ents * 1 / 21;  if (cap2 > 384000LL)  cap2 = 384000LL;
    int rc0 = (int)(cap0 / 64); if (rc0 < 1) rc0 = 1;
    int rc1 = (int)(cap1 / 64); if (rc1 < 1) rc1 = 1;
    int rc2 = (int)(cap2 / 64); if (rc2 < 1) rc2 = 1;

    unsigned long long* buf0 = (unsigned long long*)(ws + off);
    unsigned long long* buf1 = buf0 + (size_t)rc0 * 64;
    unsigned long long* buf2 = buf1 + (size_t)rc1 * 64;

    hipMemsetAsync(ws, 0, 73792, stream);   // cntM + cntF + misc + hist
    k_score<<<NBLK, 256, 0, stream>>>(obj0, cls0, obj1, cls1, obj2, cls2,
                                      cntM, hist, buf0, buf1, buf2, rc0, rc1, rc2);
    k_fb<<<64, 256, 0, stream>>>(obj0, cls0, obj1, cls1, obj2, cls2,
                                 cntM, cntF, hist, buf0, buf1, buf2, rc0, rc1, rc2);
    k_compact<<<192, 256, 0, stream>>>(cntM, cntF, misc, hist, buf0, buf1, buf2,
                                       rc0, rc1, rc2, surv);
    k_rank<<<1, 512, 0, stream>>>(misc, surv, reg0, reg1, reg2, sortf);
    k_supmat<<<6, 256, 0, stream>>>(sortf, supG);
    k_greedy<<<1, 256, 0, stream>>>(sortf, supG, (float*)d_out);
}

// Round 13
// 177.941 us; speedup vs baseline: 1.0867x; 1.0316x over previous
//
#include <hip/hip_runtime.h>
#include <stdint.h>

// ---------------- constants ----------------
#define NCLS 20
#define SURV_CAP 2048
#define NB0 600    // L0: 100 tiles(1024px) x 3 anchors x 2 class-halves
#define NB1 150    // L1: 25 x 3 x 2
#define NB2 42     // L2: 7 x 3 x 2
#define NBLK (NB0 + NB1 + NB2)
#define STG_CAP 512
#define STG_TRIG 256

__device__ __forceinline__ float sigm_fast(float x) { return 1.0f / (1.0f + __expf(-x)); }
__device__ __forceinline__ float sigm_prec(float x) { return 1.0f / (1.0f + expf(-x)); }

// ws layout:
//  cntM : u32[192*16]  (64B-padded per (L,shard))            @ 0      (12288 B)
//  cntF : u32[192*16]                                        @ 12288  (12288 B)
//  misc : u32[16]  [4..6]=survivor counts                    @ 24576  (64 B)
//  hist : u32[3*4096]                                        @ 24640  (49152 B)
//  surv : u64[3*SURV_CAP]                                    @ 73792  (49152 B)
//  sortf: f32[300*8]                                         @ 122944 (9600 B)
//  supG : u64[300*5]                                         @ 132544 (12000 B)
//  bufs : u64 regions                                        @ 147456

// ---------------- K1: streaming score pass (s > 0.7), float4 ----------------
// launch_bounds (256,4): grid is block-limited (~3 blocks/CU) so occupancy is
// unchanged, but the doubled VGPR budget lets the compiler keep more of the
// 10-class unrolled loop's float4 loads in flight (latency-bound kernel).
__global__ __launch_bounds__(256, 4) void k_score(
    const float* __restrict__ obj0, const float* __restrict__ cls0,
    const float* __restrict__ obj1, const float* __restrict__ cls1,
    const float* __restrict__ obj2, const float* __restrict__ cls2,
    unsigned int* cntM,
    unsigned long long* buf0, unsigned long long* buf1, unsigned long long* buf2,
    int rc0, int rc1, int rc2)
{
    int b = blockIdx.x;
    int L, tile, a, half, W;
    const float *obj, *cls; unsigned long long* bufL; int rc;
    if (b < NB0) {
        L = 0; tile = b % 100; a = (b / 100) % 3; half = b / 300; W = 320;
        obj = obj0; cls = cls0; bufL = buf0; rc = rc0;
    } else if (b < NB0 + NB1) {
        int bb = b - NB0;
        L = 1; tile = bb % 25; a = (bb / 25) % 3; half = bb / 75; W = 160;
        obj = obj1; cls = cls1; bufL = buf1; rc = rc1;
    } else {
        int bb = b - NB0 - NB1;
        L = 2; tile = bb % 7; a = (bb / 7) % 3; half = bb / 21; W = 80;
        obj = obj2; cls = cls2; bufL = buf2; rc = rc2;
    }
    const int P = W * W;
    const int shard = b & 63;
    const int cidx = (L * 64 + shard) * 16;
    unsigned long long* gbuf = bufL + (size_t)shard * (size_t)rc;

    __shared__ unsigned long long stage[4][STG_CAP];   // 16 KB

    const int t = threadIdx.x;
    const int wid = t >> 6, lane = t & 63;
    unsigned long long* wstage = stage[wid];
    const unsigned long long lt = (lane == 63) ? 0x7FFFFFFFFFFFFFFFull
                                               : ((1ull << lane) - 1ull);

    const int p0 = tile * 1024 + t * 4;   // 4 px/thread; P%4==0 all levels
    const bool act = p0 < P;
    const int c0 = half * 10;

    float soA = 0.f, soB = 0.f, soC = 0.f, soD = 0.f;
    if (act) {
        float4 ov = *(const float4*)(obj + (size_t)a * P + p0);
        soA = sigm_fast(ov.x); soB = sigm_fast(ov.y);
        soC = sigm_fast(ov.z); soD = sigm_fast(ov.w);
    }

    unsigned int wbase = 0;    // wave-uniform running count (register)
    #pragma unroll
    for (int cc = 0; cc < 10; cc++) {
        int c = c0 + cc;
        float s0 = -1.f, s1 = -1.f, s2 = -1.f, s3 = -1.f;
        if (act) {
            float4 cv = *(const float4*)(cls + (size_t)(a * NCLS + c) * P + p0);
            s0 = soA * sigm_fast(cv.x);
            s1 = soB * sigm_fast(cv.y);
            s2 = soC * sigm_fast(cv.z);
            s3 = soD * sigm_fast(cv.w);
        }
        bool t0 = s0 > 0.7f, t1 = s1 > 0.7f, t2 = s2 > 0.7f, t3 = s3 > 0.7f;
        unsigned long long m0 = __ballot(t0);
        unsigned long long m1 = __ballot(t1);
        unsigned long long m2 = __ballot(t2);
        unsigned long long m3 = __ballot(t3);
        if (m0 | m1 | m2 | m3) {
            unsigned int n0 = (unsigned int)__popcll(m0);
            unsigned int n1 = (unsigned int)__popcll(m1);
            unsigned int n2 = (unsigned int)__popcll(m2);
            if (t0) {
                unsigned int ti = (unsigned int)(((p0 + 0) * 3 + a) * NCLS + c);
                wstage[wbase + (unsigned int)__popcll(m0 & lt)] =
                    ((unsigned long long)__float_as_uint(s0) << 32) | (unsigned long long)(0xFFFFFFFFu - ti);
            }
            if (t1) {
                unsigned int ti = (unsigned int)(((p0 + 1) * 3 + a) * NCLS + c);
                wstage[wbase + n0 + (unsigned int)__popcll(m1 & lt)] =
                    ((unsigned long long)__float_as_uint(s1) << 32) | (unsigned long long)(0xFFFFFFFFu - ti);
            }
            if (t2) {
                unsigned int ti = (unsigned int)(((p0 + 2) * 3 + a) * NCLS + c);
                wstage[wbase + n0 + n1 + (unsigned int)__popcll(m2 & lt)] =
                    ((unsigned long long)__float_as_uint(s2) << 32) | (unsigned long long)(0xFFFFFFFFu - ti);
            }
            if (t3) {
                unsigned int ti = (unsigned int)(((p0 + 3) * 3 + a) * NCLS + c);
                wstage[wbase + n0 + n1 + n2 + (unsigned int)__popcll(m3 & lt)] =
                    ((unsigned long long)__float_as_uint(s3) << 32) | (unsigned long long)(0xFFFFFFFFu - ti);
            }
            wbase += n0 + n1 + n2 + (unsigned int)__popcll(m3);
        }
        if (wbase >= STG_TRIG) {   // wave-uniform register check; rare
            unsigned int gb = 0;
            if (lane == 0) gb = atomicAdd(&cntM[cidx], wbase);
            gb = __shfl(gb, 0);
            for (unsigned int i = lane; i < wbase; i += 64) {
                unsigned int gp = gb + i;
                if (gp < (unsigned int)rc) gbuf[gp] = wstage[i];
            }
            wbase = 0;
        }
    }
    if (wbase > 0) {   // single final flush
        unsigned int gb = 0;
        if (lane == 0) gb = atomicAdd(&cntM[cidx], wbase);
        gb = __shfl(gb, 0);
        for (unsigned int i = lane; i < wbase; i += 64) {
            unsigned int gp = gb + i;
            if (gp < (unsigned int)rc) gbuf[gp] = wstage[i];
        }
    }
}

// ---------------- K2: histogram buffered candidates (+ rare fallback rescan) ----------------
// 64 blocks; block b owns shard b of each level.
__global__ __launch_bounds__(256) void k_hist(
    const float* __restrict__ obj0, const float* __restrict__ cls0,
    const float* __restrict__ obj1, const float* __restrict__ cls1,
    const float* __restrict__ obj2, const float* __restrict__ cls2,
    unsigned int* cntM, unsigned int* cntF, unsigned int* hist,
    unsigned long long* buf0, unsigned long long* buf1, unsigned long long* buf2,
    int rc0, int rc1, int rc2)
{
    const int b = blockIdx.x;
    const int t = threadIdx.x;
    __shared__ unsigned int totS;

    for (int L = 0; L < 3; L++) {
        unsigned long long* bufL = (L == 0) ? buf0 : (L == 1 ? buf1 : buf2);
        const int rc = (L == 0) ? rc0 : (L == 1 ? rc1 : rc2);
        // level total (wave 0)
        if (t < 64) {
            unsigned int v = cntM[(L * 64 + t) * 16];
            if (v > (unsigned int)rc) v = (unsigned int)rc;
            #pragma unroll
            for (int off = 32; off; off >>= 1) v += __shfl_down(v, off);
            if (t == 0) totS = v;
        }
        __syncthreads();
        unsigned int nMine = cntM[(L * 64 + b) * 16];
        if (nMine > (unsigned int)rc) nMine = (unsigned int)rc;
        unsigned long long* myreg = bufL + (size_t)b * (size_t)rc;
        for (unsigned int i = t; i < nMine; i += 256) {
            unsigned int bits = (unsigned int)(myreg[i] >> 32);
            unsigned int bin = (bits - 0x3F000000u) >> 11;
            if (bin > 4095u) bin = 4095u;
            atomicAdd(&hist[L * 4096 + bin], 1u);
        }
        if (totS < 100u) {   // pathological-only rescan of this level (s <= 0.7)
            const float* objL = (L == 0) ? obj0 : (L == 1 ? obj1 : obj2);
            const float* clsL = (L == 0) ? cls0 : (L == 1 ? cls1 : cls2);
            const int WL = (L == 0) ? 320 : (L == 1 ? 160 : 80);
            const int PL = WL * WL;
            long long tot = (long long)PL * 3 * NCLS;
            for (long long idx = (long long)b * 256 + t; idx < tot; idx += 64 * 256) {
                int c = (int)(idx % NCLS);
                long long pa = idx / NCLS;
                int a = (int)(pa % 3);
                int p = (int)(pa / 3);
                float s = sigm_fast(objL[(size_t)a * PL + p]) *
                          sigm_fast(clsL[(size_t)(a * NCLS + c) * PL + p]);
                if (!(s > 0.7f)) {   // exact complement of main test
                    if (s >= 0.5f) {
                        unsigned int bin = (__float_as_uint(s) - 0x3F000000u) >> 11;
                        if (bin > 4095u) bin = 4095u;
                        atomicAdd(&hist[L * 4096 + bin], 1u);
                    }
                    unsigned int ti = (unsigned int)((p * 3 + a) * NCLS + c);
                    unsigned long long key =
                        ((unsigned long long)__float_as_uint(s) << 32) |
                        (unsigned long long)(0xFFFFFFFFu - ti);
                    unsigned int pos = nMine + atomicAdd(&cntF[(L * 64 + b) * 16], 1u);
                    if (pos < (unsigned int)rc) myreg[pos] = key;
                }
            }
        }
        __syncthreads();
    }
}

// ---------------- K3: compact (192 blocks; redundant threshold scan) ----------------
__global__ __launch_bounds__(256) void k_compact(
    const unsigned int* __restrict__ cntM, const unsigned int* __restrict__ cntF,
    unsigned int* misc, const unsigned int* __restrict__ hist,
    const unsigned long long* __restrict__ buf0,
    const unsigned long long* __restrict__ buf1,
    const unsigned long long* __restrict__ buf2,
    int rc0, int rc1, int rc2,
    unsigned long long* surv)
{
    __shared__ unsigned int tselS;
    const int t = threadIdx.x;
    const int lane = t & 63;
    const int r = blockIdx.x;
    const int L = r >> 6, s = r & 63;

    if (t < 64) {   // wave 0: threshold scan for this block's level
        if (t == 0) tselS = 0u;
        const unsigned int* h = hist + L * 4096;
        unsigned int sm = 0;
        for (int k = 0; k < 64; k++) sm += h[4095 - (lane * 64 + k)];
        unsigned int incl = sm;
        #pragma unroll
        for (int off = 1; off < 64; off <<= 1) {
            unsigned int u = __shfl_up(incl, off);
            if (lane >= off) incl += u;
        }
        unsigned int excl = incl - sm;
        if (excl < 100u && incl >= 100u) {
            unsigned int cum = excl;
            for (int k = 0; k < 64; k++) {
                cum += h[4095 - (lane * 64 + k)];
                if (cum >= 100u) {
                    tselS = 0x3F000000u + ((unsigned int)(4095 - (lane * 64 + k)) << 11);
                    break;
                }
            }
        }
    }
    __syncthreads();

    const unsigned long long* bufL = (L == 0) ? buf0 : (L == 1 ? buf1 : buf2);
    int rc = (L == 0) ? rc0 : (L == 1 ? rc1 : rc2);
    unsigned int n = cntM[r * 16] + cntF[r * 16];
    if (n > (unsigned int)rc) n = (unsigned int)rc;
    unsigned int ts = tselS;
    const unsigned long long* rb = bufL + (size_t)s * (size_t)rc;

    for (unsigned int i = t; i < n; i += 256) {
        unsigned long long k = rb[i];
        bool takeIt = (unsigned int)(k >> 32) >= ts;
        unsigned long long m = __ballot(takeIt);
        if (takeIt) {
            int lead = __ffsll((long long)m) - 1;
            int pref = __popcll(m & ((1ull << lane) - 1ull));
            unsigned int base = 0;
            if (lane == lead) base = atomicAdd(&misc[4 + L], (unsigned int)__popcll(m));
            base = __shfl(base, lead);
            unsigned int pos = base + (unsigned int)pref;
            if (pos < SURV_CAP) surv[L * SURV_CAP + pos] = k;
        }
    }
}

// ---------------- K4: rank-select + decode + sort -> sortf[300][8] ----------------
__global__ __launch_bounds__(512) void k_rank(
    const unsigned int* __restrict__ misc,
    const unsigned long long* __restrict__ surv,
    const float* __restrict__ reg0, const float* __restrict__ reg1, const float* __restrict__ reg2,
    float* __restrict__ sortf)
{
    const int t = threadIdx.x;
    __shared__ unsigned long long svl[SURV_CAP];
    __shared__ unsigned long long topk[300];
    __shared__ float bx[300][4];
    __shared__ float sc[300];
    __shared__ int   lb[300];
    __shared__ unsigned long long key2[300];

    for (int i = t; i < 300; i += 512) topk[i] = 0ull;
    __syncthreads();

    for (int L = 0; L < 3; L++) {
        int n = (int)misc[4 + L]; if (n > SURV_CAP) n = SURV_CAP;
        const unsigned long long* sv = surv + L * SURV_CAP;
        for (int i = t; i < n; i += 512) svl[i] = sv[i];
        __syncthreads();
        for (int i = t; i < n; i += 512) {
            unsigned long long ki = svl[i];
            int r = 0;
            for (int j = 0; j < n; j++) r += (svl[j] > ki);
            if (r < 100) topk[L * 100 + r] = ki;
        }
        __syncthreads();
    }

    const int   Wl[3] = {320, 160, 80};
    const float Sl[3] = {8.f, 16.f, 32.f};
    const float AW[3][3] = {{12.f, 19.f, 40.f}, {36.f, 76.f, 72.f}, {142.f, 192.f, 459.f}};
    const float AH[3][3] = {{16.f, 36.f, 28.f}, {75.f, 55.f, 146.f}, {110.f, 243.f, 401.f}};

    for (int i = t; i < 300; i += 512) {
        unsigned long long k = topk[i];
        int L = i / 100;
        float s = __uint_as_float((unsigned int)(k >> 32));
        unsigned int ti = 0xFFFFFFFFu - (unsigned int)k;
        float x1 = 0.f, y1 = 0.f, x2 = 0.f, y2 = 0.f; int c = 0;
        if (k != 0ull) {
            c = (int)(ti % NCLS);
            unsigned int na = ti / NCLS;
            int a = (int)(na % 3);
            int p = (int)(na / 3);
            int W = Wl[L]; int P = W * W;
            int px = p % W, py = p / W;
            const float* reg = (L == 0) ? reg0 : (L == 1 ? reg1 : reg2);
            float tx = reg[(a * 4 + 0) * P + p];
            float ty = reg[(a * 4 + 1) * P + p];
            float tw = reg[(a * 4 + 2) * P + p];
            float th = reg[(a * 4 + 3) * P + p];
            float st = Sl[L];
            float cx = (sigm_prec(tx) * 3.0f - 1.5f + ((float)px + 0.5f)) * st;
            float cy = (sigm_prec(ty) * 3.0f - 1.5f + ((float)py + 0.5f)) * st;
            float w = expf(tw) * AW[L][a];
            float h = expf(th) * AH[L][a];
            x1 = cx - 0.5f * w; y1 = cy - 0.5f * h; x2 = cx + 0.5f * w; y2 = cy + 0.5f * h;
        } else {
            s = 0.f;
        }
        bx[i][0] = x1; bx[i][1] = y1; bx[i][2] = x2; bx[i][3] = y2;
        sc[i] = s; lb[i] = c;
        key2[i] = (k & 0xFFFFFFFF00000000ull) | (unsigned long long)(299 - i);  // stable
    }
    __syncthreads();

    for (int i = t; i < 300; i += 512) {
        unsigned long long ki = key2[i];
        int r = 0;
        for (int j = 0; j < 300; j++) r += (key2[j] > ki);
        float* p = sortf + r * 8;
        p[0] = bx[i][0]; p[1] = bx[i][1]; p[2] = bx[i][2]; p[3] = bx[i][3];
        p[4] = sc[i]; p[5] = (float)lb[i]; p[6] = 0.f; p[7] = 0.f;
    }
}

// ---------------- K5: suppression matrix, 6 blocks x 256 ----------------
__global__ __launch_bounds__(256) void k_supmat(
    const float* __restrict__ sortf, unsigned long long* __restrict__ supG)
{
    __shared__ float sx1[300], sy1[300], sx2[300], sy2[300], sar[300];
    __shared__ int slb[300];
    const int t = threadIdx.x;
    for (int i = t; i < 300; i += 256) {
        float4 b = *(const float4*)(sortf + i * 8);
        sx1[i] = b.x; sy1[i] = b.y; sx2[i] = b.z; sy2[i] = b.w;
        sar[i] = (b.z - b.x) * (b.w - b.y);
        slb[i] = (int)sortf[i * 8 + 5];
    }
    __syncthreads();

    int task = blockIdx.x * 256 + t;
    if (task >= 1500) return;
    int w = task / 300, i = task - w * 300;
    float ax1 = sx1[i], ay1 = sy1[i], ax2 = sx2[i], ay2 = sy2[i], aa = sar[i];
    int al = slb[i];
    int jmax = (w == 4) ? 44 : 64;
    unsigned long long acc = 0ull;
    for (int jb = 0; jb < jmax; jb++) {
        int j = w * 64 + jb;
        float xx1 = fmaxf(ax1, sx1[j]);
        float yy1 = fmaxf(ay1, sy1[j]);
        float xx2 = fminf(ax2, sx2[j]);
        float yy2 = fminf(ay2, sy2[j]);
        float iw = fmaxf(1e-10f, xx2 - xx1);
        float ih = fmaxf(1e-10f, yy2 - yy1);
        float inter = iw * ih;
        float iou = inter / (aa + sar[j] - inter);
        if (iou > 0.5f && al == slb[j]) acc |= (1ull << jb);
    }
    supG[i * 5 + w] = acc;
}

// ---------------- K6: lane-parallel greedy NMS + output ----------------
__global__ __launch_bounds__(256) void k_greedy(
    const float* __restrict__ sortf, const unsigned long long* __restrict__ supG,
    float* __restrict__ out)
{
    const int t = threadIdx.x;
    __shared__ unsigned char keepA[300];

    if (t < 64) {
        const int l = t;
        unsigned int validb = 0;
        float s0 = sortf[(l) * 8 + 4];
        float s1 = sortf[(64 + l) * 8 + 4];
        float s2 = sortf[(128 + l) * 8 + 4];
        float s3 = sortf[(192 + l) * 8 + 4];
        float s4 = (256 + l < 300) ? sortf[(256 + l) * 8 + 4] : 0.f;
        validb |= (s0 > 0.01f) ? 1u : 0u;
        validb |= (s1 > 0.01f) ? 2u : 0u;
        validb |= (s2 > 0.01f) ? 4u : 0u;
        validb |= (s3 > 0.01f) ? 8u : 0u;
        validb |= (s4 > 0.01f) ? 16u : 0u;

        const unsigned long long* g = supG;
        unsigned long long m00 = g[(l) * 5 + 0];
        unsigned long long m10 = g[(64 + l) * 5 + 0],  m11 = g[(64 + l) * 5 + 1];
        unsigned long long m20 = g[(128 + l) * 5 + 0], m21 = g[(128 + l) * 5 + 1], m22 = g[(128 + l) * 5 + 2];
        unsigned long long m30 = g[(192 + l) * 5 + 0], m31 = g[(192 + l) * 5 + 1], m32 = g[(192 + l) * 5 + 2], m33 = g[(192 + l) * 5 + 3];
        unsigned long long m40 = 0, m41 = 0, m42 = 0, m43 = 0, m44 = 0;
        if (256 + l < 300) {
            m40 = g[(256 + l) * 5 + 0]; m41 = g[(256 + l) * 5 + 1]; m42 = g[(256 + l) * 5 + 2];
            m43 = g[(256 + l) * 5 + 3]; m44 = g[(256 + l) * 5 + 4];
        }

        unsigned int supb = 0;

        #pragma clang loop unroll(disable)
        for (int b = 0; b < 64; b++) {           // word 0
            unsigned int x = __shfl(supb | ~validb, b);
            if (!((x >> 0) & 1u)) {
                unsigned int gt = (l > b) ? 1u : 0u;
                supb |= (((unsigned int)(m00 >> b) & gt)) << 0;
                supb |= (((unsigned int)(m10 >> b) & 1u)) << 1;
                supb |= (((unsigned int)(m20 >> b) & 1u)) << 2;
                supb |= (((unsigned int)(m30 >> b) & 1u)) << 3;
                supb |= (((unsigned int)(m40 >> b) & 1u)) << 4;
            }
        }
        #pragma clang loop unroll(disable)
        for (int b = 0; b < 64; b++) {           // word 1
            unsigned int x = __shfl(supb | ~validb, b);
            if (!((x >> 1) & 1u)) {
                unsigned int gt = (l > b) ? 1u : 0u;
                supb |= (((unsigned int)(m11 >> b) & gt)) << 1;
                supb |= (((unsigned int)(m21 >> b) & 1u)) << 2;
                supb |= (((unsigned int)(m31 >> b) & 1u)) << 3;
                supb |= (((unsigned int)(m41 >> b) & 1u)) << 4;
            }
        }
        #pragma clang loop unroll(disable)
        for (int b = 0; b < 64; b++) {           // word 2
            unsigned int x = __shfl(supb | ~validb, b);
            if (!((x >> 2) & 1u)) {
                unsigned int gt = (l > b) ? 1u : 0u;
                supb |= (((unsigned int)(m22 >> b) & gt)) << 2;
                supb |= (((unsigned int)(m32 >> b) & 1u)) << 3;
                supb |= (((unsigned int)(m42 >> b) & 1u)) << 4;
            }
        }
        #pragma clang loop unroll(disable)
        for (int b = 0; b < 64; b++) {           // word 3
            unsigned int x = __shfl(supb | ~validb, b);
            if (!((x >> 3) & 1u)) {
                unsigned int gt = (l > b) ? 1u : 0u;
                supb |= (((unsigned int)(m33 >> b) & gt)) << 3;
                supb |= (((unsigned int)(m43 >> b) & 1u)) << 4;
            }
        }
        #pragma clang loop unroll(disable)
        for (int b = 0; b < 44; b++) {           // word 4 (cols 256..299)
            unsigned int x = __shfl(supb | ~validb, b);
            if (!((x >> 4) & 1u)) {
                unsigned int gt = (l > b) ? 1u : 0u;
                supb |= (((unsigned int)(m44 >> b) & gt)) << 4;
            }
        }

        unsigned int kp = (~supb) & validb;
        keepA[l]       = (unsigned char)(kp & 1u);
        keepA[64 + l]  = (unsigned char)((kp >> 1) & 1u);
        keepA[128 + l] = (unsigned char)((kp >> 2) & 1u);
        keepA[192 + l] = (unsigned char)((kp >> 3) & 1u);
        if (256 + l < 300) keepA[256 + l] = (unsigned char)((kp >> 4) & 1u);
    }
    __syncthreads();

    for (int i = t; i < 300; i += 256) {
        const float* p = sortf + i * 8;
        float kpf = keepA[i] ? 1.f : 0.f;
        out[i * 4 + 0] = p[0];
        out[i * 4 + 1] = p[1];
        out[i * 4 + 2] = p[2];
        out[i * 4 + 3] = p[3];
        out[1200 + i] = p[4] * kpf;
        out[1500 + i] = p[5];
        out[1800 + i] = kpf;
    }
}

// ---------------- launch ----------------
extern "C" void kernel_launch(void* const* d_in, const int* in_sizes, int n_in,
                              void* d_out, int out_size, void* d_ws, size_t ws_size,
                              hipStream_t stream)
{
    const float* obj0 = (const float*)d_in[0];
    const float* cls0 = (const float*)d_in[1];
    const float* reg0 = (const float*)d_in[2];
    const float* obj1 = (const float*)d_in[3];
    const float* cls1 = (const float*)d_in[4];
    const float* reg1 = (const float*)d_in[5];
    const float* obj2 = (const float*)d_in[6];
    const float* cls2 = (const float*)d_in[7];
    const float* reg2 = (const float*)d_in[8];

    char* ws = (char*)d_ws;
    unsigned int* cntM = (unsigned int*)ws;                            // 12288 B
    unsigned int* cntF = (unsigned int*)(ws + 12288);                  // 12288 B
    unsigned int* misc = (unsigned int*)(ws + 24576);                  // 64 B
    unsigned int* hist = (unsigned int*)(ws + 24640);                  // 49152 B
    unsigned long long* surv = (unsigned long long*)(ws + 73792);      // 49152 B
    float* sortf = (float*)(ws + 122944);                              // 9600 B
    unsigned long long* supG = (unsigned long long*)(ws + 132544);     // 12000 B
    const size_t off = 147456;

    size_t avail = (ws_size > off) ? (ws_size - off) : 0;
    long long ents = (long long)(avail / 8);
    long long cap0 = ents * 16 / 21; if (cap0 > 6144000LL) cap0 = 6144000LL;
    long long cap1 = ents * 4 / 21;  if (cap1 > 1536000LL) cap1 = 1536000LL;
    long long cap2 = ents * 1 / 21;  if (cap2 > 384000LL)  cap2 = 384000LL;
    int rc0 = (int)(cap0 / 64); if (rc0 < 1) rc0 = 1;
    int rc1 = (int)(cap1 / 64); if (rc1 < 1) rc1 = 1;
    int rc2 = (int)(cap2 / 64); if (rc2 < 1) rc2 = 1;

    unsigned long long* buf0 = (unsigned long long*)(ws + off);
    unsigned long long* buf1 = buf0 + (size_t)rc0 * 64;
    unsigned long long* buf2 = buf1 + (size_t)rc1 * 64;

    hipMemsetAsync(ws, 0, 73792, stream);   // cntM + cntF + misc + hist
    k_score<<<NBLK, 256, 0, stream>>>(obj0, cls0, obj1, cls1, obj2, cls2,
                                      cntM, buf0, buf1, buf2, rc0, rc1, rc2);
    k_hist<<<64, 256, 0, stream>>>(obj0, cls0, obj1, cls1, obj2, cls2,
                                   cntM, cntF, hist, buf0, buf1, buf2, rc0, rc1, rc2);
    k_compact<<<192, 256, 0, stream>>>(cntM, cntF, misc, hist, buf0, buf1, buf2,
                                       rc0, rc1, rc2, surv);
    k_rank<<<1, 512, 0, stream>>>(misc, surv, reg0, reg1, reg2, sortf);
    k_supmat<<<6, 256, 0, stream>>>(sortf, supG);
    k_greedy<<<1, 256, 0, stream>>>(sortf, supG, (float*)d_out);
}